// Round 2
// baseline (633.171 us; speedup 1.0000x reference)
//
#include <hip/hip_runtime.h>
#include <hip/hip_bf16.h>

// Problem constants
#define BB 8
#define SS 4096
#define DD 1024
#define HH 16
#define LL 6
#define FF 2048
#define VV 256
#define NC 64     // attention s-chunks (64 s each)

typedef __attribute__((ext_vector_type(8))) short bf16x8;
typedef __attribute__((ext_vector_type(4))) float f32x4;

__device__ __forceinline__ unsigned short f2bf(float f) {
    union { float f; unsigned u; } v; v.f = f;
    unsigned r = v.u + 0x7FFFu + ((v.u >> 16) & 1u);
    return (unsigned short)(r >> 16);
}

// ---------------- positional encoding (8 rows/block via angle rotation) ----------------
__global__ __launch_bounds__(256) void pe_kernel(float* __restrict__ pe) {
    int s0 = blockIdx.x * 8;
    for (int i = threadIdx.x; i < DD / 2; i += 256) {
        float div = expf((-logf(10000.0f) / (float)DD) * (float)(2 * i));
        float a0 = (float)s0 * div;
        float sa = sinf(a0), ca = cosf(a0);
        float sd = sinf(div), cd = cosf(div);
        #pragma unroll
        for (int r = 0; r < 8; ++r) {
            reinterpret_cast<float2*>(pe + (long)(s0 + r) * DD)[i] = make_float2(sa, ca);
            float sn = sa * cd + ca * sd;
            ca = ca * cd - sa * sd;
            sa = sn;
        }
    }
}

// ---------------- small GEMM (M=8), 2 waves per output column (k-split) ----------------
// block = 512 threads = 8 waves = 4 columns x 2 k-halves
// MODE 0: plain (optional A2 add, optional R1/R2 residuals)
// MODE 1: A rows LayerNorm'd on the fly (lnw/lnb over K)
// MODE 2: epilogue adds ln(lnsrc)[m][n] (lnsrc is 8 x 1024)
template <int K, int RELU, int MODE>
__global__ __launch_bounds__(512) void gemm8k(
    const float* __restrict__ A, long sA,
    const float* __restrict__ A2, long sA2,
    const float* __restrict__ W,
    const float* __restrict__ bias,
    const float* __restrict__ R1, long sR1,
    const float* __restrict__ R2, long sR2,
    const float* __restrict__ lnw, const float* __restrict__ lnb,
    const float* __restrict__ lnsrc,
    float* __restrict__ C, int N)
{
    int wave = threadIdx.x >> 6, lane = threadIdx.x & 63;
    int c = wave >> 1, kh = wave & 1;
    int n = blockIdx.x * 4 + c;          // N is always a multiple of 4
    constexpr int KH = K / 2;

    __shared__ float stat[2][8][2];
    __shared__ float part[8][8];

    float mean[8], rstd[8];
    if (MODE != 0) {
        const float* S = (MODE == 1) ? A : lnsrc;
        long ss = (MODE == 1) ? sA : 1024L;
        constexpr int SK = (MODE == 1) ? K : 1024;
        constexpr int SKH = SK / 2;
        if (wave < 2) {                  // waves 0/1 compute the two k-half stats
            #pragma unroll
            for (int m = 0; m < 8; ++m) {
                float s1 = 0.f, s2 = 0.f;
                const float4* Sr = reinterpret_cast<const float4*>(S + (long)m * ss) + kh * (SKH / 4);
                #pragma unroll
                for (int k4 = 0; k4 < SKH / 256; ++k4) {
                    float4 a = Sr[k4 * 64 + lane];
                    s1 += a.x + a.y + a.z + a.w;
                    s2 += a.x * a.x + a.y * a.y + a.z * a.z + a.w * a.w;
                }
                #pragma unroll
                for (int off = 32; off; off >>= 1) {
                    s1 += __shfl_xor(s1, off, 64);
                    s2 += __shfl_xor(s2, off, 64);
                }
                if (lane == 0) { stat[kh][m][0] = s1; stat[kh][m][1] = s2; }
            }
        }
        __syncthreads();
        constexpr float rSK = 1.f / (float)SK;
        #pragma unroll
        for (int m = 0; m < 8; ++m) {
            float s1 = stat[0][m][0] + stat[1][m][0];
            float s2 = stat[0][m][1] + stat[1][m][1];
            float mu = s1 * rSK;
            mean[m] = mu;
            rstd[m] = rsqrtf(s2 * rSK - mu * mu + 1e-5f);
        }
    }

    float acc[8] = {0.f,0.f,0.f,0.f,0.f,0.f,0.f,0.f};
    const float4* W4 = reinterpret_cast<const float4*>(W + (long)n * K) + kh * (KH / 4);
    float4 wreg[KH / 256];
    #pragma unroll
    for (int kb = 0; kb < KH / 256; ++kb) wreg[kb] = W4[kb * 64 + lane];
    #pragma unroll
    for (int kb = 0; kb < KH / 256; ++kb) {
        int k4 = kh * (KH / 4) + kb * 64 + lane;   // global float4 index
        float4 w = wreg[kb];
        float4 lw, lb;
        if (MODE == 1) {
            lw = reinterpret_cast<const float4*>(lnw)[k4];
            lb = reinterpret_cast<const float4*>(lnb)[k4];
        }
        #pragma unroll
        for (int m = 0; m < 8; ++m) {
            float4 a = reinterpret_cast<const float4*>(A + (long)m * sA)[k4];
            if (A2) {
                float4 a2 = reinterpret_cast<const float4*>(A2 + (long)m * sA2)[k4];
                a.x += a2.x; a.y += a2.y; a.z += a2.z; a.w += a2.w;
            }
            if (MODE == 1) {
                float mu = mean[m], rs = rstd[m];
                a.x = (a.x - mu) * rs * lw.x + lb.x;
                a.y = (a.y - mu) * rs * lw.y + lb.y;
                a.z = (a.z - mu) * rs * lw.z + lb.z;
                a.w = (a.w - mu) * rs * lw.w + lb.w;
            }
            acc[m] += a.x * w.x + a.y * w.y + a.z * w.z + a.w * w.w;
        }
    }
    #pragma unroll
    for (int m = 0; m < 8; ++m) {
        #pragma unroll
        for (int off = 32; off; off >>= 1) acc[m] += __shfl_xor(acc[m], off, 64);
    }
    if (lane == 0) {
        #pragma unroll
        for (int m = 0; m < 8; ++m) part[wave][m] = acc[m];
    }
    __syncthreads();
    if (kh == 0 && lane < 8) {
        int m = lane;
        float v = part[wave][m] + part[wave + 1][m] + (bias ? bias[n] : 0.f);
        if (MODE == 0) {
            if (R1) v += R1[(long)m * sR1 + n];
            if (R2) v += R2[(long)m * sR2 + n];
        }
        if (MODE == 2)
            v += (lnsrc[(long)m * 1024 + n] - mean[m]) * rstd[m] * lnw[n] + lnb[n];
        if (RELU) v = fmaxf(v, 0.f);
        C[(long)m * N + n] = v;
    }
}

// ---------------- u[b,h,:] = sum_d Q[b, h*64+d] * wk[h*64+d, :]  (bf16 out) ----------------
__global__ __launch_bounds__(256) void u_kernel(const float* __restrict__ Q,
                                                const float* __restrict__ wk,
                                                unsigned short* __restrict__ ub)
{
    int h = blockIdx.y;
    int e = blockIdx.x * 256 + threadIdx.x;
    __shared__ float qs[8][64];
    for (int idx = threadIdx.x; idx < 512; idx += 256) {
        int b = idx >> 6, d = idx & 63;
        qs[b][d] = Q[(long)b * DD + h * 64 + d];
    }
    __syncthreads();
    float acc[8] = {0.f,0.f,0.f,0.f,0.f,0.f,0.f,0.f};
    for (int d = 0; d < 64; ++d) {
        float wv = wk[(long)(h * 64 + d) * DD + e];
        #pragma unroll
        for (int b = 0; b < 8; ++b) acc[b] += qs[b][d] * wv;
    }
    #pragma unroll
    for (int b = 0; b < 8; ++b)
        ub[((long)(b * HH + h)) * DD + e] = f2bf(acc[b]);
}

// ---------------- fused attention: score + chunk-softmax + ctx partial ----------------
// grid (NC=64, BB), block 512 = 8 waves. Block owns (b, 64-s chunk).
// Phase 1: 4 s-tiles x 2 k-halves (wave = st*2+kh); partial scores -> LDS.
// Phase 2: combine halves, chunk-local softmax -> (m,l) + bf16 P in LDS (swizzled).
// Phase 3: wave owns 128 e; ctxp[h][e] = sum_s P*x via MFMA (x re-reads are cache-hot).
__global__ __launch_bounds__(512) void attn_kernel(
    const float* __restrict__ tgt, const float* __restrict__ pe,
    const unsigned short* __restrict__ ub,
    float* __restrict__ ctxp, float* __restrict__ ml)
{
    int sc = blockIdx.x, b = blockIdx.y;
    int wave = threadIdx.x >> 6, lane = threadIdx.x & 63;
    int q = lane >> 4, n = lane & 15;
    __shared__ float scs[2][16][66];         // [kh][h][s-local], padded
    __shared__ unsigned short P[16 * 64];    // bf16 probs, swizzled

    int s0 = sc * 64;

    // ---- phase 1: wave (st, kh) computes 16-s x 512-k partial scores ----
    {
        int st = wave >> 1, kh = wave & 1;
        int s = s0 + st * 16 + n;
        const float* xrow = tgt + ((long)b * SS + s) * DD + kh * 512;
        const float* prow = pe + (long)s * DD + kh * 512;
        const unsigned short* urow = ub + ((long)(b * HH) + n) * DD + kh * 512;
        f32x4 acc = {0.f, 0.f, 0.f, 0.f};
        #pragma unroll 4
        for (int ks = 0; ks < 16; ++ks) {
            int e0 = ks * 32 + q * 8;
            bf16x8 a = *reinterpret_cast<const bf16x8*>(urow + e0);   // A[m=h=n][k=e]
            float4 x0 = *reinterpret_cast<const float4*>(xrow + e0);
            float4 x1 = *reinterpret_cast<const float4*>(xrow + e0 + 4);
            float4 p0 = *reinterpret_cast<const float4*>(prow + e0);
            float4 p1 = *reinterpret_cast<const float4*>(prow + e0 + 4);
            union { short sh[8]; bf16x8 v; } bu;
            bu.sh[0] = (short)f2bf(x0.x + p0.x);
            bu.sh[1] = (short)f2bf(x0.y + p0.y);
            bu.sh[2] = (short)f2bf(x0.z + p0.z);
            bu.sh[3] = (short)f2bf(x0.w + p0.w);
            bu.sh[4] = (short)f2bf(x1.x + p1.x);
            bu.sh[5] = (short)f2bf(x1.y + p1.y);
            bu.sh[6] = (short)f2bf(x1.z + p1.z);
            bu.sh[7] = (short)f2bf(x1.w + p1.w);
            acc = __builtin_amdgcn_mfma_f32_16x16x32_bf16(a, bu.v, acc, 0, 0, 0);
        }
        // C layout: col = s (lane&15), row = h = q*4 + r
        #pragma unroll
        for (int r = 0; r < 4; ++r) scs[kh][q * 4 + r][st * 16 + n] = acc[r];
    }
    __syncthreads();

    // ---- phase 2: combine k-halves, softmax per h over 64 s; 32 threads per h ----
    {
        int h = threadIdx.x >> 5, l = threadIdx.x & 31;
        float2 v0 = *reinterpret_cast<const float2*>(&scs[0][h][l * 2]);
        float2 v1 = *reinterpret_cast<const float2*>(&scs[1][h][l * 2]);
        float a0 = (v0.x + v1.x) * 0.125f;
        float a1 = (v0.y + v1.y) * 0.125f;
        float mx = fmaxf(a0, a1);
        #pragma unroll
        for (int off = 16; off; off >>= 1) mx = fmaxf(mx, __shfl_xor(mx, off, 32));
        float e0 = expf(a0 - mx), e1 = expf(a1 - mx);
        float sum = e0 + e1;
        #pragma unroll
        for (int off = 16; off; off >>= 1) sum += __shfl_xor(sum, off, 32);
        // store bf16 P[h][l*2..+1], XOR-swizzle 16B slots within the 128B row
        unsigned d0 = (unsigned)f2bf(e0) | ((unsigned)f2bf(e1) << 16);
        char* Pb = reinterpret_cast<char*>(P);
        *reinterpret_cast<unsigned*>(Pb + ((h * 128 + l * 4) ^ ((h & 7) << 4))) = d0;
        if (l == 0) {
            long mi = ((long)sc * BB + b) * HH + h;
            ml[mi * 2] = mx;
            ml[mi * 2 + 1] = sum;
        }
    }
    __syncthreads();

    // ---- phase 3: ctx partial; wave owns e range [wave*128, +128) = 8 tiles ----
    {
        const char* Pb = reinterpret_cast<const char*>(P);
        f32x4 cacc[8];
        #pragma unroll
        for (int t = 0; t < 8; ++t) cacc[t] = (f32x4){0.f, 0.f, 0.f, 0.f};
        #pragma unroll
        for (int ks2 = 0; ks2 < 2; ++ks2) {
            int sb = ks2 * 32 + q * 8;
            // A-frag: lane (q,n) reads P[h=n][k=sb..sb+7] (16B, swizzled)
            bf16x8 a = *reinterpret_cast<const bf16x8*>(
                Pb + ((n * 128 + sb * 2) ^ ((n & 7) << 4)));
            const float* xb  = tgt + ((long)b * SS + s0 + sb) * DD;
            const float* pb2 = pe + (long)(s0 + sb) * DD;
            #pragma unroll
            for (int t = 0; t < 8; ++t) {
                int e = wave * 128 + t * 16 + n;
                union { short sh[8]; bf16x8 v; } bu;
                #pragma unroll
                for (int j = 0; j < 8; ++j)
                    bu.sh[j] = (short)f2bf(xb[(long)j * DD + e] + pb2[(long)j * DD + e]);
                cacc[t] = __builtin_amdgcn_mfma_f32_16x16x32_bf16(a, bu.v, cacc[t], 0, 0, 0);
            }
        }
        long base = (((long)sc * BB + b) * HH) * DD;
        #pragma unroll
        for (int t = 0; t < 8; ++t) {
            int e = wave * 128 + t * 16 + n;
            #pragma unroll
            for (int r = 0; r < 4; ++r)
                ctxp[base + (long)(q * 4 + r) * DD + e] = cacc[t][r];
        }
    }
}

// ---------------- reduce ctx partials over NC chunks with softmax rescale ----------------
// grid (BB*HH, 4): block handles one (b,h) row x 256-e slab
__global__ __launch_bounds__(256) void ctxred_kernel(const float* __restrict__ ctxp,
                                                     const float* __restrict__ ml,
                                                     float* __restrict__ ctx)
{
    int row = blockIdx.x;   // b*HH + h
    __shared__ float scl[NC];
    int t = threadIdx.x;
    if (t < 64) {
        float m = ml[((long)t * BB * HH + row) * 2];
        float l = ml[((long)t * BB * HH + row) * 2 + 1];
        float M = m;
        #pragma unroll
        for (int off = 32; off; off >>= 1) M = fmaxf(M, __shfl_xor(M, off, 64));
        float e = expf(m - M);
        float L = e * l;
        #pragma unroll
        for (int off = 32; off; off >>= 1) L += __shfl_xor(L, off, 64);
        scl[t] = e / L;
    }
    __syncthreads();
    int e = blockIdx.y * 256 + t;
    float s = 0.f;
    #pragma unroll 8
    for (int c = 0; c < NC; ++c)
        s += scl[c] * ctxp[((long)c * BB * HH + row) * DD + e];
    ctx[(long)row * DD + e] = s;
}

// ---------------- o[b, j] = sum_e wv[j,e]*ctx[b, j>>6, e] + bv[j]  (k-split) ----------------
__global__ __launch_bounds__(512) void ov_kernel(const float* __restrict__ ctx,
                                                 const float* __restrict__ wv,
                                                 const float* __restrict__ bv,
                                                 float* __restrict__ o)
{
    int wave = threadIdx.x >> 6, lane = threadIdx.x & 63;
    int c = wave >> 1, kh = wave & 1;
    int j = blockIdx.x * 4 + c;
    int h = j >> 6;
    __shared__ float part[8][8];
    float acc[8] = {0.f,0.f,0.f,0.f,0.f,0.f,0.f,0.f};
    const float4* w4 = reinterpret_cast<const float4*>(wv + (long)j * DD) + kh * 128;
    float4 wreg[2];
    #pragma unroll
    for (int kb = 0; kb < 2; ++kb) wreg[kb] = w4[kb * 64 + lane];
    #pragma unroll
    for (int kb = 0; kb < 2; ++kb) {
        int k4 = kh * 128 + kb * 64 + lane;
        float4 w = wreg[kb];
        #pragma unroll
        for (int b = 0; b < 8; ++b) {
            float4 a = reinterpret_cast<const float4*>(ctx + ((long)(b * HH + h)) * DD)[k4];
            acc[b] += a.x * w.x + a.y * w.y + a.z * w.z + a.w * w.w;
        }
    }
    #pragma unroll
    for (int b = 0; b < 8; ++b) {
        #pragma unroll
        for (int off = 32; off; off >>= 1) acc[b] += __shfl_xor(acc[b], off, 64);
    }
    if (lane == 0) {
        #pragma unroll
        for (int b = 0; b < 8; ++b) part[wave][b] = acc[b];
    }
    __syncthreads();
    if (kh == 0 && lane < 8) {
        int b = lane;
        o[(long)b * DD + j] = part[wave][b] + part[wave + 1][b] + bv[j];
    }
}

extern "C" void kernel_launch(void* const* d_in, const int* in_sizes, int n_in,
                              void* d_out, int out_size, void* d_ws, size_t ws_size,
                              hipStream_t stream)
{
    const float* tgt        = (const float*)d_in[0];
    const float* in_proj_w  = (const float*)d_in[1];
    const float* in_proj_b  = (const float*)d_in[2];
    const float* out_proj_w = (const float*)d_in[3];
    const float* out_proj_b = (const float*)d_in[4];
    const float* ln1_w      = (const float*)d_in[5];
    const float* ln1_b      = (const float*)d_in[6];
    const float* lin1_w     = (const float*)d_in[7];
    const float* lin1_b     = (const float*)d_in[8];
    const float* lin2_w     = (const float*)d_in[9];
    const float* lin2_b     = (const float*)d_in[10];
    const float* ln2_w      = (const float*)d_in[11];
    const float* ln2_b      = (const float*)d_in[12];
    const float* w_out      = (const float*)d_in[13];
    const float* b_out      = (const float*)d_in[14];

    float* ws = (float*)d_ws;
    long off = 0;
    float* pe   = ws + off;  off += (long)SS * DD;              // 16.8 MB
    float* ctxp = ws + off;  off += (long)NC * BB * HH * DD;    // 33.5 MB
    float* ml   = ws + off;  off += (long)NC * BB * HH * 2;     // 64 KB
    float* ctx  = ws + off;  off += (long)BB * HH * DD;         // 512 KB
    unsigned short* ub = (unsigned short*)(ws + off); off += (long)BB * HH * DD / 2;  // 256KB
    float* Q    = ws + off;  off += (long)BB * DD;
    float* o    = ws + off;  off += (long)BB * DD;
    float* vb   = ws + off;  off += (long)BB * DD;
    float* o2   = ws + off;  off += (long)BB * DD;
    float* hb   = ws + off;  off += (long)BB * FF;
    float* z    = ws + off;  off += (long)BB * DD;

    const float* tgt_last = tgt + (long)(SS - 1) * DD;
    const float* pe_last  = pe + (long)(SS - 1) * DD;

    // 1. positional encoding table
    pe_kernel<<<SS / 8, 256, 0, stream>>>(pe);

    // 2. Q = (tgt_last + pe_last) @ wq0^T + bq0
    gemm8k<1024, 0, 0><<<DD / 4, 512, 0, stream>>>(
        tgt_last, (long)SS * DD, pe_last, 0L, in_proj_w, in_proj_b,
        nullptr, 0L, nullptr, 0L, nullptr, nullptr, nullptr, Q, DD);

    // 3. u (bf16) — bk dropped (softmax-invariant)
    u_kernel<<<dim3(4, 16), 256, 0, stream>>>(Q, in_proj_w + (long)DD * DD, ub);

    // 4. fused attention (score+softmax+ctx partial) -> rescaling reduce
    attn_kernel<<<dim3(NC, BB), 512, 0, stream>>>(tgt, pe, ub, ctxp, ml);
    ctxred_kernel<<<dim3(BB * HH, 4), 256, 0, stream>>>(ctxp, ml, ctx);

    // 5. o = wv0 @ ctx + bv0
    ov_kernel<<<DD / 4, 512, 0, stream>>>(ctx, in_proj_w + 2L * DD * DD, in_proj_b + 2 * DD, o);

    // 6. layer-0 tail (ln folded into consumers)
    gemm8k<1024, 0, 0><<<DD / 4, 512, 0, stream>>>(
        o, (long)DD, nullptr, 0L, out_proj_w, out_proj_b,
        tgt_last, (long)SS * DD, pe_last, 0L, nullptr, nullptr, nullptr, o2, DD);
    gemm8k<1024, 1, 1><<<FF / 4, 512, 0, stream>>>(
        o2, (long)DD, nullptr, 0L, lin1_w, lin1_b,
        nullptr, 0L, nullptr, 0L, ln1_w, ln1_b, nullptr, hb, FF);
    gemm8k<2048, 0, 2><<<DD / 4, 512, 0, stream>>>(
        hb, (long)FF, nullptr, 0L, lin2_w, lin2_b,
        nullptr, 0L, nullptr, 0L, ln1_w, ln1_b, o2, z, DD);

    // 7. layers 1..5 (seq len 1 -> attn out = ln2(z) @ wv^T + bv)
    for (int i = 1; i < LL; ++i) {
        const float* wv_i  = in_proj_w + (long)i * 3 * DD * DD + 2L * DD * DD;
        const float* bv_i  = in_proj_b + (long)i * 3 * DD + 2 * DD;
        const float* l2w_p = ln2_w + (long)(i - 1) * DD;   // ln of layer i-1 output
        const float* l2b_p = ln2_b + (long)(i - 1) * DD;
        const float* l1w   = ln1_w + (long)i * DD;
        const float* l1b   = ln1_b + (long)i * DD;
        gemm8k<1024, 0, 1><<<DD / 4, 512, 0, stream>>>(
            z, (long)DD, nullptr, 0L, wv_i, bv_i,
            nullptr, 0L, nullptr, 0L, l2w_p, l2b_p, nullptr, vb, DD);
        gemm8k<1024, 0, 2><<<DD / 4, 512, 0, stream>>>(
            vb, (long)DD, nullptr, 0L,
            out_proj_w + (long)i * DD * DD, out_proj_b + (long)i * DD,
            nullptr, 0L, nullptr, 0L, l2w_p, l2b_p, z, o2, DD);
        gemm8k<1024, 1, 1><<<FF / 4, 512, 0, stream>>>(
            o2, (long)DD, nullptr, 0L,
            lin1_w + (long)i * FF * DD, lin1_b + (long)i * FF,
            nullptr, 0L, nullptr, 0L, l1w, l1b, nullptr, hb, FF);
        gemm8k<2048, 0, 2><<<DD / 4, 512, 0, stream>>>(
            hb, (long)FF, nullptr, 0L,
            lin2_w + (long)i * DD * FF, lin2_b + (long)i * DD,
            nullptr, 0L, nullptr, 0L, l1w, l1b, o2, z, DD);
    }

    // 8. final: out = ln2_5(z) @ w_out^T + b_out
    gemm8k<1024, 0, 1><<<VV / 4, 512, 0, stream>>>(
        z, (long)DD, nullptr, 0L, w_out, b_out,
        nullptr, 0L, nullptr, 0L,
        ln2_w + (long)(LL - 1) * DD, ln2_b + (long)(LL - 1) * DD, nullptr,
        (float*)d_out, VV);
}

// Round 3
// 611.478 us; speedup vs baseline: 1.0355x; 1.0355x over previous
//
#include <hip/hip_runtime.h>
#include <hip/hip_bf16.h>

// Problem constants
#define BB 8
#define SS 4096
#define DD 1024
#define HH 16
#define LL 6
#define FF 2048
#define VV 256
#define NC 64     // attention s-chunks (64 s each)

typedef __attribute__((ext_vector_type(8))) short bf16x8;
typedef __attribute__((ext_vector_type(4))) float f32x4;

__device__ __forceinline__ unsigned short f2bf(float f) {
    union { float f; unsigned u; } v; v.f = f;
    unsigned r = v.u + 0x7FFFu + ((v.u >> 16) & 1u);
    return (unsigned short)(r >> 16);
}

// ---------------- pe last row only (for Q and layer-0 residual) ----------------
__global__ __launch_bounds__(256) void pelast_kernel(float* __restrict__ pl) {
    for (int i = threadIdx.x; i < DD / 2; i += 256) {
        float div = expf((-logf(10000.0f) / (float)DD) * (float)(2 * i));
        float a = (float)(SS - 1) * div;
        pl[2 * i]     = sinf(a);
        pl[2 * i + 1] = cosf(a);
    }
}

// ---------------- x = bf16(tgt + pe), pe computed inline via angle rotation ----------------
// grid (SS/8, BB), 256 thr. Streams tgt once, writes bf16 x. No pe table.
__global__ __launch_bounds__(256) void xprep_kernel(const float* __restrict__ tgt,
                                                    unsigned* __restrict__ xb)
{
    int s0 = blockIdx.x * 8, b = blockIdx.y;
    for (int i = threadIdx.x; i < DD / 2; i += 256) {
        float div = expf((-logf(10000.0f) / (float)DD) * (float)(2 * i));
        float a0 = (float)s0 * div;
        float sa = sinf(a0), ca = cosf(a0);
        float sd = sinf(div), cd = cosf(div);
        #pragma unroll
        for (int r = 0; r < 8; ++r) {
            float2 t = reinterpret_cast<const float2*>(tgt + ((long)b * SS + s0 + r) * DD)[i];
            unsigned lo = f2bf(t.x + sa), hi = f2bf(t.y + ca);
            xb[((long)b * SS + s0 + r) * (DD / 2) + i] = lo | (hi << 16);
            float sn = sa * cd + ca * sd;
            ca = ca * cd - sa * sd;
            sa = sn;
        }
    }
}

// ---------------- small GEMM (M=8), one wave per output column (round-1 proven) ----------------
// MODE 0: plain (optional A2 add, optional R1/R2 residuals)
// MODE 1: A rows LayerNorm'd on the fly (lnw/lnb over K)
// MODE 2: epilogue adds ln(lnsrc)[m][n] (lnsrc is 8 x 1024)
template <int K, int RELU, int MODE>
__global__ __launch_bounds__(256) void gemm8k(
    const float* __restrict__ A, long sA,
    const float* __restrict__ A2, long sA2,
    const float* __restrict__ W,
    const float* __restrict__ bias,
    const float* __restrict__ R1, long sR1,
    const float* __restrict__ R2, long sR2,
    const float* __restrict__ lnw, const float* __restrict__ lnb,
    const float* __restrict__ lnsrc,
    float* __restrict__ C, int N)
{
    int wave = threadIdx.x >> 6, lane = threadIdx.x & 63;
    int n = blockIdx.x * 4 + wave;
    if (n >= N) return;

    float mean[8], rstd[8];
    if (MODE != 0) {
        const float* S = (MODE == 1) ? A : lnsrc;
        long ss = (MODE == 1) ? sA : 1024L;
        const int SK = (MODE == 1) ? K : 1024;
        #pragma unroll
        for (int m = 0; m < 8; ++m) {
            float s1 = 0.f, s2 = 0.f;
            const float4* Sr = reinterpret_cast<const float4*>(S + (long)m * ss);
            #pragma unroll
            for (int k4 = 0; k4 < SK / 256; ++k4) {
                float4 a = Sr[k4 * 64 + lane];
                s1 += a.x + a.y + a.z + a.w;
                s2 += a.x * a.x + a.y * a.y + a.z * a.z + a.w * a.w;
            }
            for (int off = 32; off; off >>= 1) {
                s1 += __shfl_xor(s1, off, 64);
                s2 += __shfl_xor(s2, off, 64);
            }
            float mu = s1 / (float)SK;
            mean[m] = mu;
            rstd[m] = rsqrtf(s2 / (float)SK - mu * mu + 1e-5f);
        }
    }

    float acc[8] = {0.f,0.f,0.f,0.f,0.f,0.f,0.f,0.f};
    const float4* W4 = reinterpret_cast<const float4*>(W + (long)n * K);
    float4 wv[K / 256];
    #pragma unroll
    for (int kb = 0; kb < K / 256; ++kb) wv[kb] = W4[kb * 64 + lane];
    #pragma unroll
    for (int kb = 0; kb < K / 256; ++kb) {
        int k4 = kb * 64 + lane;
        float4 w = wv[kb];
        float4 lw, lb;
        if (MODE == 1) {
            lw = reinterpret_cast<const float4*>(lnw)[k4];
            lb = reinterpret_cast<const float4*>(lnb)[k4];
        }
        #pragma unroll
        for (int m = 0; m < 8; ++m) {
            float4 a = reinterpret_cast<const float4*>(A + (long)m * sA)[k4];
            if (A2) {
                float4 a2 = reinterpret_cast<const float4*>(A2 + (long)m * sA2)[k4];
                a.x += a2.x; a.y += a2.y; a.z += a2.z; a.w += a2.w;
            }
            if (MODE == 1) {
                float mu = mean[m], rs = rstd[m];
                a.x = (a.x - mu) * rs * lw.x + lb.x;
                a.y = (a.y - mu) * rs * lw.y + lb.y;
                a.z = (a.z - mu) * rs * lw.z + lb.z;
                a.w = (a.w - mu) * rs * lw.w + lb.w;
            }
            acc[m] += a.x * w.x + a.y * w.y + a.z * w.z + a.w * w.w;
        }
    }
    #pragma unroll
    for (int m = 0; m < 8; ++m)
        for (int off = 32; off; off >>= 1) acc[m] += __shfl_xor(acc[m], off, 64);
    if (lane == 0) {
        float bs = bias ? bias[n] : 0.f;
        #pragma unroll
        for (int m = 0; m < 8; ++m) {
            float v = acc[m] + bs;
            if (MODE == 0) {
                if (R1) v += R1[(long)m * sR1 + n];
                if (R2) v += R2[(long)m * sR2 + n];
            }
            if (MODE == 2)
                v += (lnsrc[(long)m * 1024 + n] - mean[m]) * rstd[m] * lnw[n] + lnb[n];
            if (RELU) v = fmaxf(v, 0.f);
            C[(long)m * N + n] = v;
        }
    }
}

// ---------------- u[b,h,:] = sum_d Q[b, h*64+d] * wk[h*64+d, :]  (bf16 out) ----------------
__global__ __launch_bounds__(256) void u_kernel(const float* __restrict__ Q,
                                                const float* __restrict__ wk,
                                                unsigned short* __restrict__ ub)
{
    int h = blockIdx.y;
    int e = blockIdx.x * 256 + threadIdx.x;
    __shared__ float qs[8][64];
    for (int idx = threadIdx.x; idx < 512; idx += 256) {
        int b = idx >> 6, d = idx & 63;
        qs[b][d] = Q[(long)b * DD + h * 64 + d];
    }
    __syncthreads();
    float acc[8] = {0.f,0.f,0.f,0.f,0.f,0.f,0.f,0.f};
    for (int d = 0; d < 64; ++d) {
        float wv = wk[(long)(h * 64 + d) * DD + e];
        #pragma unroll
        for (int b = 0; b < 8; ++b) acc[b] += qs[b][d] * wv;
    }
    #pragma unroll
    for (int b = 0; b < 8; ++b)
        ub[((long)(b * HH + h)) * DD + e] = f2bf(acc[b]);
}

// ---------------- fused attention on precomputed bf16 x ----------------
// grid (NC=64, BB), block 512 = 8 waves, lb(512,4) for 128 VGPR.
// Phase 1: 4 s-tiles x 2 k-halves; bf16 load -> MFMA directly (no VALU chain).
// Phase 2: combine halves, chunk softmax -> (m,l) + bf16 P in LDS (swizzled).
// Phase 3: wave owns 128 e; B-frag = 8 u16 gathers from L2-hot x chunk (no f2bf).
__global__ __launch_bounds__(512, 4) void attn_kernel(
    const unsigned short* __restrict__ xb,
    const unsigned short* __restrict__ ub,
    float* __restrict__ ctxp, float* __restrict__ ml)
{
    int sc = blockIdx.x, b = blockIdx.y;
    int wave = threadIdx.x >> 6, lane = threadIdx.x & 63;
    int q = lane >> 4, n = lane & 15;
    __shared__ float scs[2][16][66];         // [kh][h][s-local], padded
    __shared__ unsigned short P[16 * 64];    // bf16 probs, swizzled

    int s0 = sc * 64;

    // ---- phase 1: wave (st, kh) computes 16-s x 512-k partial scores ----
    {
        int st = wave >> 1, kh = wave & 1;
        int s = s0 + st * 16 + n;
        const unsigned short* xrow = xb + ((long)b * SS + s) * DD + kh * 512;
        const unsigned short* urow = ub + ((long)(b * HH) + n) * DD + kh * 512;
        f32x4 acc = {0.f, 0.f, 0.f, 0.f};
        #pragma unroll
        for (int ks = 0; ks < 16; ++ks) {
            int e0 = ks * 32 + q * 8;
            bf16x8 a  = *reinterpret_cast<const bf16x8*>(urow + e0);  // A[m=h=n][k=e]
            bf16x8 xv = *reinterpret_cast<const bf16x8*>(xrow + e0);  // B[k=e][n=s]
            acc = __builtin_amdgcn_mfma_f32_16x16x32_bf16(a, xv, acc, 0, 0, 0);
        }
        // C layout: col = s (lane&15), row = h = q*4 + r
        #pragma unroll
        for (int r = 0; r < 4; ++r) scs[kh][q * 4 + r][st * 16 + n] = acc[r];
    }
    __syncthreads();

    // ---- phase 2: combine k-halves, softmax per h over 64 s; 32 threads per h ----
    {
        int h = threadIdx.x >> 5, l = threadIdx.x & 31;
        float2 v0 = *reinterpret_cast<const float2*>(&scs[0][h][l * 2]);
        float2 v1 = *reinterpret_cast<const float2*>(&scs[1][h][l * 2]);
        float a0 = (v0.x + v1.x) * 0.125f;
        float a1 = (v0.y + v1.y) * 0.125f;
        float mx = fmaxf(a0, a1);
        #pragma unroll
        for (int off = 16; off; off >>= 1) mx = fmaxf(mx, __shfl_xor(mx, off, 32));
        float e0 = expf(a0 - mx), e1 = expf(a1 - mx);
        float sum = e0 + e1;
        #pragma unroll
        for (int off = 16; off; off >>= 1) sum += __shfl_xor(sum, off, 32);
        // store bf16 P[h][l*2..+1], XOR-swizzle 16B slots within the 128B row
        unsigned d0 = (unsigned)f2bf(e0) | ((unsigned)f2bf(e1) << 16);
        char* Pb = reinterpret_cast<char*>(P);
        *reinterpret_cast<unsigned*>(Pb + ((h * 128 + l * 4) ^ ((h & 7) << 4))) = d0;
        if (l == 0) {
            long mi = ((long)sc * BB + b) * HH + h;
            ml[mi * 2] = mx;
            ml[mi * 2 + 1] = sum;
        }
    }
    __syncthreads();

    // ---- phase 3: ctx partial; wave owns e range [wave*128, +128) = 8 tiles ----
    {
        const char* Pb = reinterpret_cast<const char*>(P);
        bf16x8 pa[2];
        #pragma unroll
        for (int ks2 = 0; ks2 < 2; ++ks2) {
            int sb = ks2 * 32 + q * 8;
            pa[ks2] = *reinterpret_cast<const bf16x8*>(
                Pb + ((n * 128 + sb * 2) ^ ((n & 7) << 4)));   // A[m=h=n][k=s]
        }
        f32x4 cacc[8];
        #pragma unroll
        for (int t = 0; t < 8; ++t) cacc[t] = (f32x4){0.f, 0.f, 0.f, 0.f};
        #pragma unroll
        for (int ks2 = 0; ks2 < 2; ++ks2) {
            int sb = ks2 * 32 + q * 8;
            const unsigned short* xbase = xb + ((long)b * SS + s0 + sb) * DD;
            #pragma unroll
            for (int t = 0; t < 8; ++t) {
                int e = wave * 128 + t * 16 + n;
                union { unsigned short sh[8]; bf16x8 v; } bu;
                #pragma unroll
                for (int j = 0; j < 8; ++j)
                    bu.sh[j] = xbase[(long)j * DD + e];        // B[k=s][n=e], L2-hot
                cacc[t] = __builtin_amdgcn_mfma_f32_16x16x32_bf16(pa[ks2], bu.v, cacc[t], 0, 0, 0);
            }
        }
        long base = (((long)sc * BB + b) * HH) * DD;
        #pragma unroll
        for (int t = 0; t < 8; ++t) {
            int e = wave * 128 + t * 16 + n;
            #pragma unroll
            for (int r = 0; r < 4; ++r)
                ctxp[base + (long)(q * 4 + r) * DD + e] = cacc[t][r];
        }
    }
}

// ---------------- reduce ctx partials over NC chunks with softmax rescale ----------------
// grid (BB*HH, 4): block handles one (b,h) row x 256-e slab
__global__ __launch_bounds__(256) void ctxred_kernel(const float* __restrict__ ctxp,
                                                     const float* __restrict__ ml,
                                                     float* __restrict__ ctx)
{
    int row = blockIdx.x;   // b*HH + h
    __shared__ float scl[NC];
    int t = threadIdx.x;
    if (t < 64) {
        float m = ml[((long)t * BB * HH + row) * 2];
        float l = ml[((long)t * BB * HH + row) * 2 + 1];
        float M = m;
        #pragma unroll
        for (int off = 32; off; off >>= 1) M = fmaxf(M, __shfl_xor(M, off, 64));
        float e = expf(m - M);
        float L = e * l;
        #pragma unroll
        for (int off = 32; off; off >>= 1) L += __shfl_xor(L, off, 64);
        scl[t] = e / L;
    }
    __syncthreads();
    int e = blockIdx.y * 256 + t;
    float s = 0.f;
    #pragma unroll 8
    for (int c = 0; c < NC; ++c)
        s += scl[c] * ctxp[((long)c * BB * HH + row) * DD + e];
    ctx[(long)row * DD + e] = s;
}

// ---------------- o[b, j] = sum_e wv[j,e]*ctx[b, j>>6, e] + bv[j] ----------------
__global__ __launch_bounds__(256) void ov_kernel(const float* __restrict__ ctx,
                                                 const float* __restrict__ wv,
                                                 const float* __restrict__ bv,
                                                 float* __restrict__ o)
{
    int wave = threadIdx.x >> 6, lane = threadIdx.x & 63;
    int j = blockIdx.x * 4 + wave;
    if (j >= DD) return;
    int h = j >> 6;
    float acc[8] = {0.f,0.f,0.f,0.f,0.f,0.f,0.f,0.f};
    const float4* w4 = reinterpret_cast<const float4*>(wv + (long)j * DD);
    float4 wreg[4];
    #pragma unroll
    for (int kb = 0; kb < 4; ++kb) wreg[kb] = w4[kb * 64 + lane];
    #pragma unroll
    for (int kb = 0; kb < 4; ++kb) {
        int k4 = kb * 64 + lane;
        float4 w = wreg[kb];
        #pragma unroll
        for (int b = 0; b < 8; ++b) {
            float4 a = reinterpret_cast<const float4*>(ctx + ((long)(b * HH + h)) * DD)[k4];
            acc[b] += a.x * w.x + a.y * w.y + a.z * w.z + a.w * w.w;
        }
    }
    #pragma unroll
    for (int b = 0; b < 8; ++b)
        for (int off = 32; off; off >>= 1) acc[b] += __shfl_xor(acc[b], off, 64);
    if (lane == 0) {
        float bs = bv[j];
        #pragma unroll
        for (int b = 0; b < 8; ++b) o[(long)b * DD + j] = acc[b] + bs;
    }
}

extern "C" void kernel_launch(void* const* d_in, const int* in_sizes, int n_in,
                              void* d_out, int out_size, void* d_ws, size_t ws_size,
                              hipStream_t stream)
{
    const float* tgt        = (const float*)d_in[0];
    const float* in_proj_w  = (const float*)d_in[1];
    const float* in_proj_b  = (const float*)d_in[2];
    const float* out_proj_w = (const float*)d_in[3];
    const float* out_proj_b = (const float*)d_in[4];
    const float* ln1_w      = (const float*)d_in[5];
    const float* ln1_b      = (const float*)d_in[6];
    const float* lin1_w     = (const float*)d_in[7];
    const float* lin1_b     = (const float*)d_in[8];
    const float* lin2_w     = (const float*)d_in[9];
    const float* lin2_b     = (const float*)d_in[10];
    const float* ln2_w      = (const float*)d_in[11];
    const float* ln2_b      = (const float*)d_in[12];
    const float* w_out      = (const float*)d_in[13];
    const float* b_out      = (const float*)d_in[14];

    float* ws = (float*)d_ws;
    long off = 0;
    unsigned short* xb = (unsigned short*)(ws + off); off += (long)BB * SS * DD / 2;  // 67 MB
    float* ctxp = ws + off;  off += (long)NC * BB * HH * DD;    // 33.5 MB
    float* ml   = ws + off;  off += (long)NC * BB * HH * 2;     // 64 KB
    float* ctx  = ws + off;  off += (long)BB * HH * DD;         // 512 KB
    unsigned short* ub = (unsigned short*)(ws + off); off += (long)BB * HH * DD / 2;  // 256KB
    float* pl   = ws + off;  off += DD;                         // pe last row
    float* Q    = ws + off;  off += (long)BB * DD;
    float* o    = ws + off;  off += (long)BB * DD;
    float* vb   = ws + off;  off += (long)BB * DD;
    float* o2   = ws + off;  off += (long)BB * DD;
    float* hb   = ws + off;  off += (long)BB * FF;
    float* z    = ws + off;  off += (long)BB * DD;

    const float* tgt_last = tgt + (long)(SS - 1) * DD;

    // 1. pe last row + bf16 x = tgt + pe (pe inline, no table)
    pelast_kernel<<<1, 256, 0, stream>>>(pl);
    xprep_kernel<<<dim3(SS / 8, BB), 256, 0, stream>>>(tgt, (unsigned*)xb);

    // 2. Q = (tgt_last + pe_last) @ wq0^T + bq0
    gemm8k<1024, 0, 0><<<DD / 4, 256, 0, stream>>>(
        tgt_last, (long)SS * DD, pl, 0L, in_proj_w, in_proj_b,
        nullptr, 0L, nullptr, 0L, nullptr, nullptr, nullptr, Q, DD);

    // 3. u (bf16) — bk dropped (softmax-invariant)
    u_kernel<<<dim3(4, 16), 256, 0, stream>>>(Q, in_proj_w + (long)DD * DD, ub);

    // 4. fused attention (score+softmax+ctx partial) -> rescaling reduce
    attn_kernel<<<dim3(NC, BB), 512, 0, stream>>>(xb, ub, ctxp, ml);
    ctxred_kernel<<<dim3(BB * HH, 4), 256, 0, stream>>>(ctxp, ml, ctx);

    // 5. o = wv0 @ ctx + bv0
    ov_kernel<<<DD / 4, 256, 0, stream>>>(ctx, in_proj_w + 2L * DD * DD, in_proj_b + 2 * DD, o);

    // 6. layer-0 tail (ln folded into consumers)
    gemm8k<1024, 0, 0><<<DD / 4, 256, 0, stream>>>(
        o, (long)DD, nullptr, 0L, out_proj_w, out_proj_b,
        tgt_last, (long)SS * DD, pl, 0L, nullptr, nullptr, nullptr, o2, DD);
    gemm8k<1024, 1, 1><<<FF / 4, 256, 0, stream>>>(
        o2, (long)DD, nullptr, 0L, lin1_w, lin1_b,
        nullptr, 0L, nullptr, 0L, ln1_w, ln1_b, nullptr, hb, FF);
    gemm8k<2048, 0, 2><<<DD / 4, 256, 0, stream>>>(
        hb, (long)FF, nullptr, 0L, lin2_w, lin2_b,
        nullptr, 0L, nullptr, 0L, ln1_w, ln1_b, o2, z, DD);

    // 7. layers 1..5 (seq len 1 -> attn out = ln2(z) @ wv^T + bv)
    for (int i = 1; i < LL; ++i) {
        const float* wv_i  = in_proj_w + (long)i * 3 * DD * DD + 2L * DD * DD;
        const float* bv_i  = in_proj_b + (long)i * 3 * DD + 2 * DD;
        const float* l2w_p = ln2_w + (long)(i - 1) * DD;   // ln of layer i-1 output
        const float* l2b_p = ln2_b + (long)(i - 1) * DD;
        const float* l1w   = ln1_w + (long)i * DD;
        const float* l1b   = ln1_b + (long)i * DD;
        gemm8k<1024, 0, 1><<<DD / 4, 256, 0, stream>>>(
            z, (long)DD, nullptr, 0L, wv_i, bv_i,
            nullptr, 0L, nullptr, 0L, l2w_p, l2b_p, nullptr, vb, DD);
        gemm8k<1024, 0, 2><<<DD / 4, 256, 0, stream>>>(
            vb, (long)DD, nullptr, 0L,
            out_proj_w + (long)i * DD * DD, out_proj_b + (long)i * DD,
            nullptr, 0L, nullptr, 0L, l2w_p, l2b_p, z, o2, DD);
        gemm8k<1024, 1, 1><<<FF / 4, 256, 0, stream>>>(
            o2, (long)DD, nullptr, 0L,
            lin1_w + (long)i * FF * DD, lin1_b + (long)i * FF,
            nullptr, 0L, nullptr, 0L, l1w, l1b, nullptr, hb, FF);
        gemm8k<2048, 0, 2><<<DD / 4, 256, 0, stream>>>(
            hb, (long)FF, nullptr, 0L,
            lin2_w + (long)i * DD * FF, lin2_b + (long)i * DD,
            nullptr, 0L, nullptr, 0L, l1w, l1b, o2, z, DD);
    }

    // 8. final: out = ln2_5(z) @ w_out^T + b_out
    gemm8k<1024, 0, 1><<<VV / 4, 256, 0, stream>>>(
        z, (long)DD, nullptr, 0L, w_out, b_out,
        nullptr, 0L, nullptr, 0L,
        ln2_w + (long)(LL - 1) * DD, ln2_b + (long)(LL - 1) * DD, nullptr,
        (float*)d_out, VV);
}